// Round 7
// baseline (178.742 us; speedup 1.0000x reference)
//
#include <hip/hip_runtime.h>

// Problem constants
#define BB   4
#define SEQ  2048
#define EMB  512
#define NH   8
#define HD   64
// SCALE = HD^-0.5 = 0.125; folded with log2(e) into Q at qkv epilogue:
#define QSCALE 0.18033688011f   // 0.125 * log2(e)

typedef __bf16 bf16x8 __attribute__((ext_vector_type(8)));
typedef float  f32x4  __attribute__((ext_vector_type(4)));

__device__ __forceinline__ short f2bf(float f) {
  union { float f; unsigned u; } v; v.f = f;
  unsigned r = v.u + 0x7fffu + ((v.u >> 16) & 1u);   // RNE
  return (short)(r >> 16);
}

// packed fp32x2 -> bf16x2 (RNE), hardware on gfx950
__device__ __forceinline__ unsigned pk_bf16(float a, float b) {
#if __has_builtin(__builtin_amdgcn_cvt_pk_bf16_f32)
  typedef __bf16 bf16v2 __attribute__((ext_vector_type(2)));
  union { bf16v2 v; unsigned u; } cv;
  cv.v = __builtin_amdgcn_cvt_pk_bf16_f32(a, b);
  return cv.u;
#else
  return (unsigned)(unsigned short)f2bf(a) | ((unsigned)(unsigned short)f2bf(b) << 16);
#endif
}

__device__ __forceinline__ float fexp2(float x) {
#if __has_builtin(__builtin_amdgcn_exp2f)
  return __builtin_amdgcn_exp2f(x);
#else
  return exp2f(x);
#endif
}

__device__ __forceinline__ void gl_lds16(const void* g, void* l) {
  __builtin_amdgcn_global_load_lds(
      (const __attribute__((address_space(1))) unsigned int*)g,
      (__attribute__((address_space(3))) unsigned int*)l, 16, 0, 0);
}

// ---------------------------------------------------------------- fused casts
__global__ __launch_bounds__(256) void cast_all(const float* __restrict__ x,
                                                const float* __restrict__ wq,
                                                const float* __restrict__ wo,
                                                short* __restrict__ xb,
                                                short* __restrict__ wqb,
                                                short* __restrict__ wob) {
  int i = blockIdx.x * 256 + threadIdx.x;
  const float* src; short* dst; int off;
  if (i < 1048576)      { src = x;  dst = xb;  off = i; }
  else if (i < 1245184) { src = wq; dst = wqb; off = i - 1048576; }
  else                  { src = wo; dst = wob; off = i - 1245184; }
  float4 v = ((const float4*)src)[off];
  uint2 o; o.x = pk_bf16(v.x, v.y); o.y = pk_bf16(v.z, v.w);
  *(uint2*)&dst[off * 4] = o;
}

// ---------------------------------------------------------------- QKV projection
// BK=32, double-buffered LDS, ONE barrier per K-iter (prefetch overlaps compute).
// C[m,f] = sum_e x[m,e]*Wqkv[f,e] + b[f]; Q gets *QSCALE; scatter Q,K (b,h,n,d), V^T (b,h,d,n)
__global__ __launch_bounds__(256) void qkv_gemm(const short* __restrict__ A,
                                                const short* __restrict__ W,
                                                const float* __restrict__ bias,
                                                short* __restrict__ qo,
                                                short* __restrict__ ko,
                                                short* __restrict__ vto) {
  __shared__ __align__(16) short As[2][128 * 32];
  __shared__ __align__(16) short Bs[2][128 * 32];
  const int tid  = threadIdx.x;
  const int lane = tid & 63, wave = tid >> 6;
  const int wm = wave >> 1, wf = wave & 1;
  const int col = lane & 15, quad = lane >> 4;
  const int m0 = blockIdx.x * 128, f0 = blockIdx.y * 128;

  // staging sources: 512 granules (16B) per tile, 2 per thread; advance by 32 per iter
  const short* aSrc[2]; const short* wSrc[2];
#pragma unroll
  for (int rd = 0; rd < 2; ++rd) {
    int slot = rd * 256 + tid;
    int row = slot >> 2, c8 = (slot & 3) * 8;
    aSrc[rd] = A + (size_t)(m0 + row) * 512 + c8;
    wSrc[rd] = W + (size_t)(f0 + row) * 512 + c8;
  }
  // fragment LDS element offsets (m97-style BK=32 layout)
  int aOff[4], bOff[4];
#pragma unroll
  for (int i = 0; i < 4; ++i) {
    aOff[i] = (wm * 64 + i * 16 + col) * 32 + quad * 8;
    bOff[i] = (wf * 64 + i * 16 + col) * 32 + quad * 8;
  }

  f32x4 acc[4][4];
#pragma unroll
  for (int i = 0; i < 4; ++i)
#pragma unroll
    for (int j = 0; j < 4; ++j)
#pragma unroll
      for (int r = 0; r < 4; ++r) acc[i][j][r] = 0.f;

  // prefetch iter 0 -> buf 0
#pragma unroll
  for (int rd = 0; rd < 2; ++rd) {
    gl_lds16(aSrc[rd], (char*)As[0] + rd * 4096 + wave * 1024);
    gl_lds16(wSrc[rd], (char*)Bs[0] + rd * 4096 + wave * 1024);
    aSrc[rd] += 32; wSrc[rd] += 32;
  }

#pragma unroll 1
  for (int it2 = 0; it2 < 8; ++it2) {
#pragma unroll
    for (int ph = 0; ph < 2; ++ph) {
      const int cur = ph, nxt = ph ^ 1;
      __syncthreads();   // drains cur's loads (in flight a full iter) + nxt readers done
      if (it2 < 7 || ph == 0) {
#pragma unroll
        for (int rd = 0; rd < 2; ++rd) {
          gl_lds16(aSrc[rd], (char*)As[nxt] + rd * 4096 + wave * 1024);
          gl_lds16(wSrc[rd], (char*)Bs[nxt] + rd * 4096 + wave * 1024);
          aSrc[rd] += 32; wSrc[rd] += 32;
        }
      }
      bf16x8 af[4], bw[4];
#pragma unroll
      for (int i = 0; i < 4; ++i) af[i] = *(const bf16x8*)&As[cur][aOff[i]];
#pragma unroll
      for (int j = 0; j < 4; ++j) bw[j] = *(const bf16x8*)&Bs[cur][bOff[j]];
#pragma unroll
      for (int i = 0; i < 4; ++i)
#pragma unroll
        for (int j = 0; j < 4; ++j)
          acc[i][j] = __builtin_amdgcn_mfma_f32_16x16x32_bf16(af[i], bw[j], acc[i][j], 0, 0, 0);
    }
  }

  // epilogue: C/D layout row = quad*4+r, col = lane&15
#pragma unroll
  for (int j = 0; j < 4; ++j) {
    const int f = f0 + wf * 64 + j * 16 + col;
    const float bv = bias[f];
    const int sIdx = f >> 9;          // 0=Q 1=K 2=V (wave-uniform)
    const int h = (f >> 6) & 7;
    const int d = f & 63;
#pragma unroll
    for (int i = 0; i < 4; ++i) {
      const int mbase = m0 + wm * 64 + i * 16 + quad * 4;
      const int b = mbase >> 11;
      const int n = mbase & 2047;
      const size_t bh = (size_t)(b * NH + h);
      if (sIdx == 2) {
        uint2 pk;
        pk.x = pk_bf16(acc[i][j][0] + bv, acc[i][j][1] + bv);
        pk.y = pk_bf16(acc[i][j][2] + bv, acc[i][j][3] + bv);
        *(uint2*)&vto[(bh * HD + d) * SEQ + n] = pk;     // V^T: (bh, d, n)
      } else if (sIdx == 0) {
#pragma unroll
        for (int r = 0; r < 4; ++r)
          qo[(bh * SEQ + n + r) * HD + d] = f2bf((acc[i][j][r] + bv) * QSCALE);
      } else {
#pragma unroll
        for (int r = 0; r < 4; ++r)
          ko[(bh * SEQ + n + r) * HD + d] = f2bf(acc[i][j][r] + bv);
      }
    }
  }
}

// ---------------------------------------------------------------- flash attention (R3 + zero-C)
// grid 512 = 32 bh x 16 qtiles(128q); 4 waves x 32 q; KV tile 64;
// S^T operand-swap; fixed-max softmax (exp2, scale pre-folded into Q).
__global__ __launch_bounds__(256) void attn_kernel(const short* __restrict__ q,
                                                   const short* __restrict__ k,
                                                   const short* __restrict__ vt,
                                                   short* __restrict__ o) {
  __shared__ __align__(16) short Ks[64 * 64];        // XOR-swizzled
  __shared__ __align__(16) short Vs[64 * 64];        // XOR-swizzled
  __shared__ __align__(16) short Ps[4 * 32 * 72];    // per-wave P[q][key], stride 72
  __shared__ float Ls[4 * 32];
  const int tid  = threadIdx.x;
  const int lane = tid & 63, wave = tid >> 6;
  const int col = lane & 15, quad = lane >> 4;
  const int bh = blockIdx.x & 31;
  const int q0 = (blockIdx.x >> 5) * 128;
  const size_t bhBase = (size_t)bh * SEQ * HD;

  // Q fragments (B-operand): lane holds Q'[q=col][d=quad*8+j]
  bf16x8 qf[2][2];
#pragma unroll
  for (int t = 0; t < 2; ++t)
#pragma unroll
    for (int ks = 0; ks < 2; ++ks)
      qf[t][ks] = *(const bf16x8*)&q[bhBase +
          (size_t)(q0 + wave * 32 + t * 16 + col) * HD + ks * 32 + quad * 8];

  // staging pointers (tile-invariant dst; source advances per tile)
  const int rowL = tid >> 3,         cbL = (tid & 7) ^ (rowL & 7);
  const int rowH = (256 + tid) >> 3, cbH = (tid & 7) ^ (rowH & 7);
  const short* ksrcL = k  + bhBase + (size_t)rowL * HD + cbL * 8;
  const short* ksrcH = k  + bhBase + (size_t)rowH * HD + cbH * 8;
  const short* vsrcL = vt + bhBase + (size_t)rowL * SEQ + cbL * 8;
  const short* vsrcH = vt + bhBase + (size_t)rowH * SEQ + cbH * 8;
  char* ldsKL = (char*)Ks + wave * 1024;
  char* ldsKH = (char*)Ks + 4096 + wave * 1024;
  char* ldsVL = (char*)Vs + wave * 1024;
  char* ldsVH = (char*)Vs + 4096 + wave * 1024;

  // hoisted LDS element offsets (loop-invariant)
  const int wbase = wave * 32 * 72;
  int kfO[4][2], vfO[2][4], pwO[4][2], prO[2][2];
#pragma unroll
  for (int kt = 0; kt < 4; ++kt)
#pragma unroll
    for (int ks = 0; ks < 2; ++ks)
      kfO[kt][ks] = (kt * 16 + col) * 64 + (((ks * 4 + quad) ^ (col & 7)) * 8);
#pragma unroll
  for (int ks2 = 0; ks2 < 2; ++ks2)
#pragma unroll
    for (int nt = 0; nt < 4; ++nt)
      vfO[ks2][nt] = (nt * 16 + col) * 64 + (((ks2 * 4 + quad) ^ (col & 7)) * 8);
#pragma unroll
  for (int kt = 0; kt < 4; ++kt)
#pragma unroll
    for (int t = 0; t < 2; ++t)
      pwO[kt][t] = wbase + (t * 16 + col) * 72 + kt * 16 + quad * 4;
#pragma unroll
  for (int t = 0; t < 2; ++t)
#pragma unroll
    for (int ks2 = 0; ks2 < 2; ++ks2)
      prO[t][ks2] = wbase + (t * 16 + col) * 72 + ks2 * 32 + quad * 8;

  f32x4 oacc[2][4];
#pragma unroll
  for (int t = 0; t < 2; ++t)
#pragma unroll
    for (int nt = 0; nt < 4; ++nt)
#pragma unroll
      for (int r = 0; r < 4; ++r) oacc[t][nt][r] = 0.f;
  float lpart[2] = {0.f, 0.f};
  const f32x4 z4 = {0.f, 0.f, 0.f, 0.f};   // zero C for first QK MFMA (no per-tile re-init)

  for (int n0 = 0; n0 < SEQ; n0 += 64) {
    __syncthreads();
    gl_lds16(ksrcL, ldsKL);
    gl_lds16(ksrcH, ldsKH);
    gl_lds16(vsrcL, ldsVL);
    gl_lds16(vsrcH, ldsVH);
    ksrcL += 64 * HD; ksrcH += 64 * HD; vsrcL += 64; vsrcH += 64;
    __syncthreads();

    // S^T = K Q'^T : C[m=key][n=q]; ks=0 uses zero-C
    f32x4 sacc[4][2];
#pragma unroll
    for (int kt = 0; kt < 4; ++kt) {
      bf16x8 kf0 = *(const bf16x8*)&Ks[kfO[kt][0]];
      bf16x8 kf1 = *(const bf16x8*)&Ks[kfO[kt][1]];
#pragma unroll
      for (int t = 0; t < 2; ++t)
        sacc[kt][t] = __builtin_amdgcn_mfma_f32_16x16x32_bf16(kf0, qf[t][0], z4, 0, 0, 0);
#pragma unroll
      for (int t = 0; t < 2; ++t)
        sacc[kt][t] = __builtin_amdgcn_mfma_f32_16x16x32_bf16(kf1, qf[t][1], sacc[kt][t], 0, 0, 0);
    }

    // p = exp2(s'), partial row-sums, pack P
#pragma unroll
    for (int kt = 0; kt < 4; ++kt)
#pragma unroll
      for (int t = 0; t < 2; ++t) {
        float p0 = fexp2(sacc[kt][t][0]);
        float p1 = fexp2(sacc[kt][t][1]);
        float p2 = fexp2(sacc[kt][t][2]);
        float p3 = fexp2(sacc[kt][t][3]);
        lpart[t] += (p0 + p1) + (p2 + p3);
        uint2 w; w.x = pk_bf16(p0, p1); w.y = pk_bf16(p2, p3);
        *(uint2*)&Ps[pwO[kt][t]] = w;
      }

    // O += P V
#pragma unroll
    for (int ks2 = 0; ks2 < 2; ++ks2) {
      bf16x8 pf[2];
#pragma unroll
      for (int t = 0; t < 2; ++t) pf[t] = *(const bf16x8*)&Ps[prO[t][ks2]];
#pragma unroll
      for (int nt = 0; nt < 4; ++nt) {
        bf16x8 vf = *(const bf16x8*)&Vs[vfO[ks2][nt]];
#pragma unroll
        for (int t = 0; t < 2; ++t)
          oacc[t][nt] = __builtin_amdgcn_mfma_f32_16x16x32_bf16(pf[t], vf, oacc[t][nt], 0, 0, 0);
      }
    }
  }

  // final row-sum reduce across quads
#pragma unroll
  for (int t = 0; t < 2; ++t) {
    lpart[t] += __shfl_xor(lpart[t], 16);
    lpart[t] += __shfl_xor(lpart[t], 32);
    Ls[wave * 32 + t * 16 + col] = lpart[t];
  }

  const int b = bh >> 3, h = bh & 7;
#pragma unroll
  for (int t = 0; t < 2; ++t) {
    float rl[4];
#pragma unroll
    for (int r = 0; r < 4; ++r)
      rl[r] = 1.0f / Ls[wave * 32 + t * 16 + quad * 4 + r];
#pragma unroll
    for (int nt = 0; nt < 4; ++nt)
#pragma unroll
      for (int r = 0; r < 4; ++r) {
        const int n = q0 + wave * 32 + t * 16 + quad * 4 + r;
        o[((size_t)(b * SEQ + n)) * EMB + h * HD + nt * 16 + col] = f2bf(oacc[t][nt][r] * rl[r]);
      }
  }
}

// ---------------------------------------------------------------- out projection
// 64x128 tiles, BK=32 double-buffered, one barrier per iter.
__global__ __launch_bounds__(256) void proj_gemm(const short* __restrict__ A,
                                                 const short* __restrict__ W,
                                                 const float* __restrict__ bias,
                                                 float* __restrict__ out) {
  __shared__ __align__(16) short As[2][64 * 32];
  __shared__ __align__(16) short Bs[2][128 * 32];
  const int tid  = threadIdx.x;
  const int lane = tid & 63, wave = tid >> 6;
  const int wm = wave >> 1, wf = wave & 1;
  const int col = lane & 15, quad = lane >> 4;
  const int m0 = blockIdx.x * 64, f0 = blockIdx.y * 128;

  // A: 256 granules (1/thread); B: 512 granules (2/thread)
  const short* aSrc = A + (size_t)(m0 + (tid >> 2)) * 512 + (tid & 3) * 8;
  const short* wSrc[2];
#pragma unroll
  for (int rd = 0; rd < 2; ++rd) {
    int slot = rd * 256 + tid;
    int row = slot >> 2, c8 = (slot & 3) * 8;
    wSrc[rd] = W + (size_t)(f0 + row) * 512 + c8;
  }
  int aOff[2], bOff[4];
#pragma unroll
  for (int i = 0; i < 2; ++i) aOff[i] = (wm * 32 + i * 16 + col) * 32 + quad * 8;
#pragma unroll
  for (int j = 0; j < 4; ++j) bOff[j] = (wf * 64 + j * 16 + col) * 32 + quad * 8;

  f32x4 acc[2][4];
#pragma unroll
  for (int i = 0; i < 2; ++i)
#pragma unroll
    for (int j = 0; j < 4; ++j)
#pragma unroll
      for (int r = 0; r < 4; ++r) acc[i][j][r] = 0.f;

  // prefetch iter 0 -> buf 0
  gl_lds16(aSrc, (char*)As[0] + wave * 1024); aSrc += 32;
#pragma unroll
  for (int rd = 0; rd < 2; ++rd) {
    gl_lds16(wSrc[rd], (char*)Bs[0] + rd * 4096 + wave * 1024);
    wSrc[rd] += 32;
  }

#pragma unroll 1
  for (int it2 = 0; it2 < 8; ++it2) {
#pragma unroll
    for (int ph = 0; ph < 2; ++ph) {
      const int cur = ph, nxt = ph ^ 1;
      __syncthreads();
      if (it2 < 7 || ph == 0) {
        gl_lds16(aSrc, (char*)As[nxt] + wave * 1024); aSrc += 32;
#pragma unroll
        for (int rd = 0; rd < 2; ++rd) {
          gl_lds16(wSrc[rd], (char*)Bs[nxt] + rd * 4096 + wave * 1024);
          wSrc[rd] += 32;
        }
      }
      bf16x8 af[2], bw[4];
#pragma unroll
      for (int i = 0; i < 2; ++i) af[i] = *(const bf16x8*)&As[cur][aOff[i]];
#pragma unroll
      for (int j = 0; j < 4; ++j) bw[j] = *(const bf16x8*)&Bs[cur][bOff[j]];
#pragma unroll
      for (int i = 0; i < 2; ++i)
#pragma unroll
        for (int j = 0; j < 4; ++j)
          acc[i][j] = __builtin_amdgcn_mfma_f32_16x16x32_bf16(af[i], bw[j], acc[i][j], 0, 0, 0);
    }
  }

#pragma unroll
  for (int j = 0; j < 4; ++j) {
    const int f = f0 + wf * 64 + j * 16 + col;
    const float bv = bias[f];
#pragma unroll
    for (int i = 0; i < 2; ++i) {
      const int mbase = m0 + wm * 32 + i * 16 + quad * 4;
#pragma unroll
      for (int r = 0; r < 4; ++r)
        out[(size_t)(mbase + r) * 512 + f] = acc[i][j][r] + bv;
    }
  }
}

// ---------------------------------------------------------------- launch
extern "C" void kernel_launch(void* const* d_in, const int* in_sizes, int n_in,
                              void* d_out, int out_size, void* d_ws, size_t ws_size,
                              hipStream_t stream) {
  (void)in_sizes; (void)n_in; (void)out_size; (void)ws_size;
  const float* x     = (const float*)d_in[0];
  const float* w_qkv = (const float*)d_in[1];
  const float* b_qkv = (const float*)d_in[2];
  const float* w_out = (const float*)d_in[3];
  const float* b_out = (const float*)d_in[4];
  float* out = (float*)d_out;

  char* ws = (char*)d_ws;
  short* xb    = (short*)(ws + 0);         // 8,388,608
  short* wqkvb = (short*)(ws + 8388608);   // 1,572,864
  short* woutb = (short*)(ws + 9961472);   //   524,288
  short* qb    = (short*)(ws + 10485760);  // 8,388,608  (b,h,n,d)  pre-scaled by QSCALE
  short* kb    = (short*)(ws + 18874368);  // 8,388,608  (b,h,n,d)
  short* vtb   = (short*)(ws + 27262976);  // 8,388,608  (b,h,d,n)
  short* ob    = (short*)(ws + 35651584);  // 8,388,608  (b,n,e)

  cast_all<<<5120, 256, 0, stream>>>(x, w_qkv, w_out, xb, wqkvb, woutb);
  qkv_gemm<<<dim3(64, 12), 256, 0, stream>>>(xb, wqkvb, b_qkv, qb, kb, vtb);
  attn_kernel<<<512, 256, 0, stream>>>(qb, kb, vtb, ob);
  proj_gemm<<<dim3(128, 4), 256, 0, stream>>>(ob, woutb, b_out, out);
}

// Round 8
// 175.323 us; speedup vs baseline: 1.0195x; 1.0195x over previous
//
#include <hip/hip_runtime.h>

// Problem constants
#define BB   4
#define SEQ  2048
#define EMB  512
#define NH   8
#define HD   64
// SCALE = HD^-0.5 = 0.125; folded with log2(e) into Q at qkv epilogue:
#define QSCALE 0.18033688011f   // 0.125 * log2(e)

typedef __bf16 bf16x8 __attribute__((ext_vector_type(8)));
typedef float  f32x4  __attribute__((ext_vector_type(4)));
typedef short  s16x4  __attribute__((ext_vector_type(4)));

__device__ __forceinline__ short f2bf(float f) {
  union { float f; unsigned u; } v; v.f = f;
  unsigned r = v.u + 0x7fffu + ((v.u >> 16) & 1u);   // RNE
  return (short)(r >> 16);
}

// packed fp32x2 -> bf16x2 (RNE), hardware on gfx950
__device__ __forceinline__ unsigned pk_bf16(float a, float b) {
#if __has_builtin(__builtin_amdgcn_cvt_pk_bf16_f32)
  typedef __bf16 bf16v2 __attribute__((ext_vector_type(2)));
  union { bf16v2 v; unsigned u; } cv;
  cv.v = __builtin_amdgcn_cvt_pk_bf16_f32(a, b);
  return cv.u;
#else
  return (unsigned)(unsigned short)f2bf(a) | ((unsigned)(unsigned short)f2bf(b) << 16);
#endif
}

__device__ __forceinline__ float fexp2(float x) {
#if __has_builtin(__builtin_amdgcn_exp2f)
  return __builtin_amdgcn_exp2f(x);
#else
  return exp2f(x);
#endif
}

__device__ __forceinline__ void gl_lds16(const void* g, void* l) {
  __builtin_amdgcn_global_load_lds(
      (const __attribute__((address_space(1))) unsigned int*)g,
      (__attribute__((address_space(3))) unsigned int*)l, 16, 0, 0);
}

// PV matmul, K=16: A-operand lane layout (k=quad*4+j) == QK C-layout (key=quad*4+r),
// so P never leaves registers.
__device__ __forceinline__ f32x4 mfma_pv16(s16x4 a, s16x4 b, f32x4 c) {
#if __has_builtin(__builtin_amdgcn_mfma_f32_16x16x16bf16_1k)
  return __builtin_amdgcn_mfma_f32_16x16x16bf16_1k(a, b, c, 0, 0, 0);
#else
  // zero-pad to K=32 (upper-half A zeros kill the garbage B upper half)
  union { bf16x8 v; s16x4 h[2]; } A, B;
  A.h[0] = a; A.h[1] = (s16x4){0, 0, 0, 0};
  B.h[0] = b; B.h[1] = (s16x4){0, 0, 0, 0};
  return __builtin_amdgcn_mfma_f32_16x16x32_bf16(A.v, B.v, c, 0, 0, 0);
#endif
}

// ---------------------------------------------------------------- fused casts
__global__ __launch_bounds__(256) void cast_all(const float* __restrict__ x,
                                                const float* __restrict__ wq,
                                                const float* __restrict__ wo,
                                                short* __restrict__ xb,
                                                short* __restrict__ wqb,
                                                short* __restrict__ wob) {
  int i = blockIdx.x * 256 + threadIdx.x;
  const float* src; short* dst; int off;
  if (i < 1048576)      { src = x;  dst = xb;  off = i; }
  else if (i < 1245184) { src = wq; dst = wqb; off = i - 1048576; }
  else                  { src = wo; dst = wob; off = i - 1245184; }
  float4 v = ((const float4*)src)[off];
  uint2 o; o.x = pk_bf16(v.x, v.y); o.y = pk_bf16(v.z, v.w);
  *(uint2*)&dst[off * 4] = o;
}

// ---------------------------------------------------------------- QKV projection (R3)
__global__ __launch_bounds__(256) void qkv_gemm(const short* __restrict__ A,
                                                const short* __restrict__ W,
                                                const float* __restrict__ bias,
                                                short* __restrict__ qo,
                                                short* __restrict__ ko,
                                                short* __restrict__ vto) {
  __shared__ __align__(16) short As[128 * 64];
  __shared__ __align__(16) short Bs[128 * 64];
  const int tid  = threadIdx.x;
  const int lane = tid & 63, wave = tid >> 6;
  const int wm = wave >> 1, wf = wave & 1;
  const int col = lane & 15, quad = lane >> 4;
  const int m0 = blockIdx.x * 128, f0 = blockIdx.y * 128;

  const short* aSrc[4]; const short* wSrc[4];
#pragma unroll
  for (int rd = 0; rd < 4; ++rd) {
    int slot = rd * 256 + tid;
    int row = slot >> 3;
    int cb  = (slot & 7) ^ (row & 7);
    aSrc[rd] = A + (size_t)(m0 + row) * 512 + cb * 8;
    wSrc[rd] = W + (size_t)(f0 + row) * 512 + cb * 8;
  }
  int aOff[2][4], bOff[2][4];
#pragma unroll
  for (int kk = 0; kk < 2; ++kk)
#pragma unroll
    for (int i = 0; i < 4; ++i) {
      aOff[kk][i] = (wm * 64 + i * 16 + col) * 64 + (((kk * 4 + quad) ^ (col & 7)) * 8);
      bOff[kk][i] = (wf * 64 + i * 16 + col) * 64 + (((kk * 4 + quad) ^ (col & 7)) * 8);
    }

  f32x4 acc[4][4];
#pragma unroll
  for (int i = 0; i < 4; ++i)
#pragma unroll
    for (int j = 0; j < 4; ++j)
#pragma unroll
      for (int r = 0; r < 4; ++r) acc[i][j][r] = 0.f;

  for (int kt = 0; kt < 8; ++kt) {
    __syncthreads();
#pragma unroll
    for (int rd = 0; rd < 4; ++rd) {
      gl_lds16(aSrc[rd], (char*)As + rd * 4096 + wave * 1024);
      gl_lds16(wSrc[rd], (char*)Bs + rd * 4096 + wave * 1024);
      aSrc[rd] += 64; wSrc[rd] += 64;
    }
    __syncthreads();
#pragma unroll
    for (int kk = 0; kk < 2; ++kk) {
      bf16x8 af[4], bw[4];
#pragma unroll
      for (int i = 0; i < 4; ++i) af[i] = *(const bf16x8*)&As[aOff[kk][i]];
#pragma unroll
      for (int j = 0; j < 4; ++j) bw[j] = *(const bf16x8*)&Bs[bOff[kk][j]];
#pragma unroll
      for (int i = 0; i < 4; ++i)
#pragma unroll
        for (int j = 0; j < 4; ++j)
          acc[i][j] = __builtin_amdgcn_mfma_f32_16x16x32_bf16(af[i], bw[j], acc[i][j], 0, 0, 0);
    }
  }

#pragma unroll
  for (int j = 0; j < 4; ++j) {
    const int f = f0 + wf * 64 + j * 16 + col;
    const float bv = bias[f];
    const int sIdx = f >> 9;          // 0=Q 1=K 2=V (wave-uniform)
    const int h = (f >> 6) & 7;
    const int d = f & 63;
#pragma unroll
    for (int i = 0; i < 4; ++i) {
      const int mbase = m0 + wm * 64 + i * 16 + quad * 4;
      const int b = mbase >> 11;
      const int n = mbase & 2047;
      const size_t bh = (size_t)(b * NH + h);
      if (sIdx == 2) {
        uint2 pk;
        pk.x = pk_bf16(acc[i][j][0] + bv, acc[i][j][1] + bv);
        pk.y = pk_bf16(acc[i][j][2] + bv, acc[i][j][3] + bv);
        *(uint2*)&vto[(bh * HD + d) * SEQ + n] = pk;     // V^T: (bh, d, n)
      } else if (sIdx == 0) {
#pragma unroll
        for (int r = 0; r < 4; ++r)
          qo[(bh * SEQ + n + r) * HD + d] = f2bf((acc[i][j][r] + bv) * QSCALE);
      } else {
#pragma unroll
        for (int r = 0; r < 4; ++r)
          ko[(bh * SEQ + n + r) * HD + d] = f2bf(acc[i][j][r] + bv);
      }
    }
  }
}

// ---------------------------------------------------------------- flash attention v8
// grid 512 = 32 bh x 16 qtiles(128q); 4 waves x 32 q.  NO BARRIERS in the K-loop:
// each wave stages its own private K/V tile (LDS 4x16 KB) and self-paces, so
// QK / exp / PV phases of different waves overlap (m114).  PV uses K=16 MFMA with
// P passed register-only (A-layout k=quad*4+j == C-layout key=quad*4+r).
__global__ __launch_bounds__(256) void attn_kernel(const short* __restrict__ q,
                                                   const short* __restrict__ k,
                                                   const short* __restrict__ vt,
                                                   short* __restrict__ o) {
  __shared__ __align__(16) short Ks[4][64 * 64];   // per-wave, XOR-swizzled (key,d)
  __shared__ __align__(16) short Vs[4][64 * 64];   // per-wave, XOR-swizzled (d,key)
  __shared__ float Ls[4 * 32];
  const int tid  = threadIdx.x;
  const int lane = tid & 63, wave = tid >> 6;
  const int col = lane & 15, quad = lane >> 4;
  const int bh = blockIdx.x & 31;
  const int q0 = (blockIdx.x >> 5) * 128;
  const size_t bhBase = (size_t)bh * SEQ * HD;

  // Q fragments (B-operand): lane holds Q'[q=col][d=quad*8+j]
  bf16x8 qf[2][2];
#pragma unroll
  for (int t = 0; t < 2; ++t)
#pragma unroll
    for (int ks = 0; ks < 2; ++ks)
      qf[t][ks] = *(const bf16x8*)&q[bhBase +
          (size_t)(q0 + wave * 32 + t * 16 + col) * HD + ks * 32 + quad * 8];

  // per-wave staging: granule g = (lane&7) ^ row, row = c*8 + (lane>>3)
  const int srow = lane >> 3, sg = lane & 7;
  const short* ksrc = k  + bhBase + (size_t)srow * HD  + (sg ^ srow) * 8;
  const short* vsrc = vt + bhBase + (size_t)srow * SEQ + (sg ^ srow) * 8;
  char* kdst = (char*)Ks[wave];
  char* vdst = (char*)Vs[wave];
  const short* Kw = Ks[wave];
  const short* Vw = Vs[wave];

  // hoisted K-fragment offsets
  int kfO[4][2];
#pragma unroll
  for (int kt = 0; kt < 4; ++kt)
#pragma unroll
    for (int ks = 0; ks < 2; ++ks)
      kfO[kt][ks] = (kt * 16 + col) * 64 + (((ks * 4 + quad) ^ (col & 7)) * 8);
  // V-fragment (b64) offset pieces: row = nt*16+col, granule (kt*2 + quad>>1)^(col&7), half = quad&1
  const int qh = quad >> 1, ql4 = (quad & 1) * 4, cx = col & 7;

  f32x4 oacc[2][4];
#pragma unroll
  for (int t = 0; t < 2; ++t)
#pragma unroll
    for (int nt = 0; nt < 4; ++nt)
#pragma unroll
      for (int r = 0; r < 4; ++r) oacc[t][nt][r] = 0.f;
  float lpart[2] = {0.f, 0.f};
  const f32x4 z4 = {0.f, 0.f, 0.f, 0.f};

  for (int n0 = 0; n0 < SEQ; n0 += 64) {
    // stage this wave's K/V tile (8 + 8 DMA granule-rows of 1 KB)
#pragma unroll
    for (int c = 0; c < 8; ++c)
      gl_lds16(ksrc + (size_t)c * (8 * HD), kdst + c * 1024);
#pragma unroll
    for (int c = 0; c < 8; ++c)
      gl_lds16(vsrc + (size_t)c * (8 * SEQ), vdst + c * 1024);
    ksrc += 64 * HD; vsrc += 64;
    __builtin_amdgcn_s_waitcnt(0x3F70);   // vmcnt(0): DMA landed; wave-local, no barrier

#pragma unroll
    for (int kt = 0; kt < 4; ++kt) {
      // S^T tile: C[m=key(16)][n=q], keys kt*16..+15
      bf16x8 kf0 = *(const bf16x8*)&Kw[kfO[kt][0]];
      bf16x8 kf1 = *(const bf16x8*)&Kw[kfO[kt][1]];
      f32x4 s0 = __builtin_amdgcn_mfma_f32_16x16x32_bf16(kf0, qf[0][0], z4, 0, 0, 0);
      f32x4 s1 = __builtin_amdgcn_mfma_f32_16x16x32_bf16(kf0, qf[1][0], z4, 0, 0, 0);
      s0 = __builtin_amdgcn_mfma_f32_16x16x32_bf16(kf1, qf[0][1], s0, 0, 0, 0);
      s1 = __builtin_amdgcn_mfma_f32_16x16x32_bf16(kf1, qf[1][1], s1, 0, 0, 0);

      // p = exp2(s'); pack to A-frag (k=quad*4+j) register-only
      s16x4 a4[2];
#pragma unroll
      for (int t = 0; t < 2; ++t) {
        const f32x4 sv = t ? s1 : s0;
        float p0 = fexp2(sv[0]);
        float p1 = fexp2(sv[1]);
        float p2 = fexp2(sv[2]);
        float p3 = fexp2(sv[3]);
        lpart[t] += (p0 + p1) + (p2 + p3);
        union { s16x4 v; unsigned u[2]; } pa;
        pa.u[0] = pk_bf16(p0, p1);
        pa.u[1] = pk_bf16(p2, p3);
        a4[t] = pa.v;
      }

      // O += P(16 keys) x V : B-frag b64 from private V^T tile
#pragma unroll
      for (int nt = 0; nt < 4; ++nt) {
        s16x4 vf = *(const s16x4*)&Vw[(nt * 16 + col) * 64 +
                                      (((kt * 2 + qh) ^ cx) * 8) + ql4];
#pragma unroll
        for (int t = 0; t < 2; ++t)
          oacc[t][nt] = mfma_pv16(a4[t], vf, oacc[t][nt]);
      }
    }
  }

  // final row-sum reduce across quads (wave-internal)
#pragma unroll
  for (int t = 0; t < 2; ++t) {
    lpart[t] += __shfl_xor(lpart[t], 16);
    lpart[t] += __shfl_xor(lpart[t], 32);
    Ls[wave * 32 + t * 16 + col] = lpart[t];
  }

  const int b = bh >> 3, h = bh & 7;
#pragma unroll
  for (int t = 0; t < 2; ++t) {
    float rl[4];
#pragma unroll
    for (int r = 0; r < 4; ++r)
      rl[r] = 1.0f / Ls[wave * 32 + t * 16 + quad * 4 + r];
#pragma unroll
    for (int nt = 0; nt < 4; ++nt)
#pragma unroll
      for (int r = 0; r < 4; ++r) {
        const int n = q0 + wave * 32 + t * 16 + quad * 4 + r;
        o[((size_t)(b * SEQ + n)) * EMB + h * HD + nt * 16 + col] = f2bf(oacc[t][nt][r] * rl[r]);
      }
  }
}

// ---------------------------------------------------------------- out projection (R3)
__global__ __launch_bounds__(256) void proj_gemm(const short* __restrict__ A,
                                                 const short* __restrict__ W,
                                                 const float* __restrict__ bias,
                                                 float* __restrict__ out) {
  __shared__ __align__(16) short As[64 * 64];
  __shared__ __align__(16) short Bs[128 * 64];
  const int tid  = threadIdx.x;
  const int lane = tid & 63, wave = tid >> 6;
  const int wm = wave >> 1, wf = wave & 1;
  const int col = lane & 15, quad = lane >> 4;
  const int m0 = blockIdx.x * 64, f0 = blockIdx.y * 128;

  const short* aSrc[2]; const short* wSrc[4];
#pragma unroll
  for (int rd = 0; rd < 2; ++rd) {
    int slot = rd * 256 + tid;
    int row = slot >> 3;
    int cb  = (slot & 7) ^ (row & 7);
    aSrc[rd] = A + (size_t)(m0 + row) * 512 + cb * 8;
  }
#pragma unroll
  for (int rd = 0; rd < 4; ++rd) {
    int slot = rd * 256 + tid;
    int row = slot >> 3;
    int cb  = (slot & 7) ^ (row & 7);
    wSrc[rd] = W + (size_t)(f0 + row) * 512 + cb * 8;
  }
  int aOff[2][2], bOff[2][4];
#pragma unroll
  for (int kk = 0; kk < 2; ++kk) {
#pragma unroll
    for (int i = 0; i < 2; ++i)
      aOff[kk][i] = (wm * 32 + i * 16 + col) * 64 + (((kk * 4 + quad) ^ (col & 7)) * 8);
#pragma unroll
    for (int j = 0; j < 4; ++j)
      bOff[kk][j] = (wf * 64 + j * 16 + col) * 64 + (((kk * 4 + quad) ^ (col & 7)) * 8);
  }

  f32x4 acc[2][4];
#pragma unroll
  for (int i = 0; i < 2; ++i)
#pragma unroll
    for (int j = 0; j < 4; ++j)
#pragma unroll
      for (int r = 0; r < 4; ++r) acc[i][j][r] = 0.f;

  for (int kt = 0; kt < 8; ++kt) {
    __syncthreads();
#pragma unroll
    for (int rd = 0; rd < 2; ++rd) {
      gl_lds16(aSrc[rd], (char*)As + rd * 4096 + wave * 1024);
      aSrc[rd] += 64;
    }
#pragma unroll
    for (int rd = 0; rd < 4; ++rd) {
      gl_lds16(wSrc[rd], (char*)Bs + rd * 4096 + wave * 1024);
      wSrc[rd] += 64;
    }
    __syncthreads();
#pragma unroll
    for (int kk = 0; kk < 2; ++kk) {
      bf16x8 af[2], bw[4];
#pragma unroll
      for (int i = 0; i < 2; ++i) af[i] = *(const bf16x8*)&As[aOff[kk][i]];
#pragma unroll
      for (int j = 0; j < 4; ++j) bw[j] = *(const bf16x8*)&Bs[bOff[kk][j]];
#pragma unroll
      for (int i = 0; i < 2; ++i)
#pragma unroll
        for (int j = 0; j < 4; ++j)
          acc[i][j] = __builtin_amdgcn_mfma_f32_16x16x32_bf16(af[i], bw[j], acc[i][j], 0, 0, 0);
    }
  }

#pragma unroll
  for (int j = 0; j < 4; ++j) {
    const int f = f0 + wf * 64 + j * 16 + col;
    const float bv = bias[f];
#pragma unroll
    for (int i = 0; i < 2; ++i) {
      const int mbase = m0 + wm * 32 + i * 16 + quad * 4;
#pragma unroll
      for (int r = 0; r < 4; ++r)
        out[(size_t)(mbase + r) * 512 + f] = acc[i][j][r] + bv;
    }
  }
}

// ---------------------------------------------------------------- launch
extern "C" void kernel_launch(void* const* d_in, const int* in_sizes, int n_in,
                              void* d_out, int out_size, void* d_ws, size_t ws_size,
                              hipStream_t stream) {
  (void)in_sizes; (void)n_in; (void)out_size; (void)ws_size;
  const float* x     = (const float*)d_in[0];
  const float* w_qkv = (const float*)d_in[1];
  const float* b_qkv = (const float*)d_in[2];
  const float* w_out = (const float*)d_in[3];
  const float* b_out = (const float*)d_in[4];
  float* out = (float*)d_out;

  char* ws = (char*)d_ws;
  short* xb    = (short*)(ws + 0);         // 8,388,608
  short* wqkvb = (short*)(ws + 8388608);   // 1,572,864
  short* woutb = (short*)(ws + 9961472);   //   524,288
  short* qb    = (short*)(ws + 10485760);  // 8,388,608  (b,h,n,d)  pre-scaled by QSCALE
  short* kb    = (short*)(ws + 18874368);  // 8,388,608  (b,h,n,d)
  short* vtb   = (short*)(ws + 27262976);  // 8,388,608  (b,h,d,n)
  short* ob    = (short*)(ws + 35651584);  // 8,388,608  (b,n,e)

  cast_all<<<5120, 256, 0, stream>>>(x, w_qkv, w_out, xb, wqkvb, woutb);
  qkv_gemm<<<dim3(64, 12), 256, 0, stream>>>(xb, wqkvb, b_qkv, qb, kb, vtb);
  attn_kernel<<<512, 256, 0, stream>>>(qb, kb, vtb, ob);
  proj_gemm<<<dim3(128, 4), 256, 0, stream>>>(ob, woutb, b_out, out);
}